// Round 4
// baseline (322.879 us; speedup 1.0000x reference)
//
#include <hip/hip_runtime.h>

#define NDET 5000
#define NCLS 80
#define DSTR 84      // 4 box coords + 80 class scores
#define TOPK 1000
#define CROP 14
#define NPIX (CROP * CROP)   // 196
#define C    256
#define NPAIR (TOPK * NPIX)  // 196000

#define JCHUNK 250
#define ICHUNK 256

typedef float v4f __attribute__((ext_vector_type(4)));

// ---------------- Phase 0: zero the entire output (write-once stream) -------
// 1000*196*256 floats = 12,544,000 float4. 6125 blocks x 256 thr x 8 f4 exact.
__global__ __launch_bounds__(256) void zero_kernel(float* __restrict__ out) {
    v4f* o = (v4f*)out;
    int base = blockIdx.x * 2048 + threadIdx.x;
    v4f z = {0.0f, 0.0f, 0.0f, 0.0f};
    #pragma unroll
    for (int k = 0; k < 8; ++k) o[base + k * 256] = z;
}

// ---------------- Phase 1a: scores + init rank + init worklist counter ------
__global__ void scores_kernel(const float* __restrict__ det, float* __restrict__ scores,
                              int* __restrict__ rank, int* __restrict__ counter) {
    int i = blockIdx.x * blockDim.x + threadIdx.x;
    if (i == 0) *counter = 0;
    if (i >= NDET) return;
    const float* row = det + i * DSTR + 4;
    float m = row[0];
    #pragma unroll
    for (int c = 1; c < NCLS; ++c) m = fmaxf(m, row[c]);
    scores[i] = m;
    rank[i] = 0;
}

// ---------------- Phase 1b: distributed rank counting -----------------------
// rank(i) = #{j : s_j > s_i} + #{j < i : s_j == s_i}   (jax.lax.top_k order)
__global__ __launch_bounds__(ICHUNK) void rank_kernel(const float* __restrict__ scores,
                                                      int* __restrict__ rank) {
    __shared__ float s[JCHUNK];
    int jbase = blockIdx.y * JCHUNK;
    for (int t = threadIdx.x; t < JCHUNK; t += blockDim.x) s[t] = scores[jbase + t];
    __syncthreads();
    int i = blockIdx.x * ICHUNK + threadIdx.x;
    if (i >= NDET) return;
    float my = scores[i];
    int r = 0;
    #pragma unroll 5
    for (int t = 0; t < JCHUNK; ++t) {
        float v = s[t];
        int j = jbase + t;
        r += (v > my) | ((v == my) & (j < i));
    }
    atomicAdd(&rank[i], r);
}

__global__ void scatter_kernel(const int* __restrict__ rank, int* __restrict__ topk_idx) {
    int i = blockIdx.x * blockDim.x + threadIdx.x;
    if (i >= NDET) return;
    int r = rank[i];
    if (r < TOPK) topk_idx[r] = i;
}

// ---------------- Phase 1c: levels + stable counting-sort via packed scan ---
__global__ __launch_bounds__(1024) void order_kernel(const float* __restrict__ det,
                                                     const int* __restrict__ topk_idx,
                                                     int* __restrict__ slot_det,
                                                     int* __restrict__ slot_level) {
    __shared__ unsigned long long wave_tot[16];
    int r = threadIdx.x;
    int di = 0, L = 0;
    unsigned long long key = 0;
    if (r < TOPK) {
        di = topk_idx[r];
        const float* b = det + di * DSTR;
        float w = b[2] - b[0];
        float h = b[3] - b[1];
        float sz = sqrtf(w * h);
        float lf = floorf(1.0f + log2f(sz / 224.0f + 1e-7f));
        lf = fminf(fmaxf(lf, 0.0f), 4.0f);
        L = (int)lf;
        key = 1ULL << (12 * L);
    }
    unsigned long long incl = key;
    #pragma unroll
    for (int d = 1; d < 64; d <<= 1) {
        unsigned long long up = __shfl_up(incl, d, 64);
        if ((r & 63) >= d) incl += up;
    }
    int wave = r >> 6;
    if ((r & 63) == 63) wave_tot[wave] = incl;
    __syncthreads();
    unsigned long long waveoff = 0, total = 0;
    for (int w = 0; w < 16; ++w) {
        unsigned long long t = wave_tot[w];
        if (w < wave) waveoff += t;
        total += t;
    }
    if (r < TOPK) {
        unsigned long long excl = waveoff + incl - key;
        int base = 0;
        for (int l = 0; l < L; ++l) base += (int)((total >> (12 * l)) & 0xFFF);
        int within = (int)((excl >> (12 * L)) & 0xFFF);
        int pos = base + within;
        slot_det[pos] = di;
        slot_level[pos] = L;
    }
}

// ---------------- shared sampling math (must match reference bit-for-bit) ---
__device__ __forceinline__ void sample_coords(const float* __restrict__ b, float hf,
                                              int py, int px, float& ys, float& xs) {
    float x1n = b[0] / hf, y1n = b[1] / hf;
    float x2n = b[2] / hf, y2n = b[3] / hf;   // W == H per level
    float ty = (float)py / 13.0f;
    float tx = (float)px / 13.0f;
    ys = (y1n + (y2n - y1n) * ty) * hf;
    xs = (x1n + (x2n - x1n) * tx) * hf;
}

__device__ __forceinline__ int level_H(int L) {
    return 256 >> L;
}

// ---------------- Phase 2a: build worklist of valid (slot, pixel) pairs -----
__global__ __launch_bounds__(256) void worklist_kernel(
    const float* __restrict__ det,
    const int* __restrict__ slot_det, const int* __restrict__ slot_level,
    int* __restrict__ counter, int* __restrict__ worklist)
{
    int idx = blockIdx.x * blockDim.x + threadIdx.x;
    int lane = threadIdx.x & 63;
    bool valid = false;
    int entry = 0;
    if (idx < NPAIR) {
        int s = idx / NPIX;
        int p = idx - s * NPIX;
        int py = p / CROP, px = p - py * CROP;
        int L = slot_level[s];
        int di = slot_det[s];
        float hf = (float)(level_H(L) - 1);
        float ys, xs;
        sample_coords(det + di * DSTR, hf, py, px, ys, xs);
        valid = (ys >= 0.0f) & (ys <= hf) & (xs >= 0.0f) & (xs <= hf);
        entry = (s << 8) | p;
    }
    unsigned long long mask = __ballot(valid);
    int myoff = __popcll(mask & ((1ULL << lane) - 1ULL));
    int cnt = __popcll(mask);
    int base = 0;
    if (lane == 0) base = atomicAdd(counter, cnt);
    base = __shfl(base, 0, 64);
    if (valid) worklist[base + myoff] = entry;
}

// ---------------- Phase 2b: gather + bilinear blend for valid pixels --------
#define GBLOCKS 1024
#define GWAVES (GBLOCKS * 4)

__global__ __launch_bounds__(256) void gather_kernel(
    const float* __restrict__ det,
    const float* __restrict__ p0, const float* __restrict__ p1,
    const float* __restrict__ p2, const float* __restrict__ p3,
    const float* __restrict__ p4,
    const int* __restrict__ slot_det, const int* __restrict__ slot_level,
    const int* __restrict__ counter, const int* __restrict__ worklist,
    float* __restrict__ out)
{
    int lane = threadIdx.x & 63;
    int w = blockIdx.x * 4 + (threadIdx.x >> 6);
    int count = *counter;
    for (int e = w; e < count; e += GWAVES) {
        int ent = worklist[e];
        int s = ent >> 8;
        int p = ent & 255;
        int py = p / CROP, px = p - py * CROP;
        int di = slot_det[s];
        int L  = slot_level[s];
        const float* feat;
        switch (L) {
            case 0:  feat = p0; break;
            case 1:  feat = p1; break;
            case 2:  feat = p2; break;
            case 3:  feat = p3; break;
            default: feat = p4; break;
        }
        int H = level_H(L);
        float hf = (float)(H - 1);
        float ys, xs;
        sample_coords(det + di * DSTR, hf, py, px, ys, xs);

        float y0f = floorf(ys), x0f = floorf(xs);
        float ly = ys - y0f,    lx = xs - x0f;
        int y0i = (int)fminf(fmaxf(y0f,        0.0f), hf);
        int y1i = (int)fminf(fmaxf(y0f + 1.0f, 0.0f), hf);
        int x0i = (int)fminf(fmaxf(x0f,        0.0f), hf);
        int x1i = (int)fminf(fmaxf(x0f + 1.0f, 0.0f), hf);

        v4f f00 = ((const v4f*)(feat + (size_t)(y0i * H + x0i) * C))[lane];
        v4f f01 = ((const v4f*)(feat + (size_t)(y0i * H + x1i) * C))[lane];
        v4f f10 = ((const v4f*)(feat + (size_t)(y1i * H + x0i) * C))[lane];
        v4f f11 = ((const v4f*)(feat + (size_t)(y1i * H + x1i) * C))[lane];

        v4f top = f00 + (f01 - f00) * lx;
        v4f bot = f10 + (f11 - f10) * lx;
        v4f o   = top + (bot - top) * ly;
        ((v4f*)(out + (size_t)(s * NPIX + p) * C))[lane] = o;
    }
}

extern "C" void kernel_launch(void* const* d_in, const int* in_sizes, int n_in,
                              void* d_out, int out_size, void* d_ws, size_t ws_size,
                              hipStream_t stream) {
    const float* det = (const float*)d_in[0];
    const float* p0  = (const float*)d_in[1];
    const float* p1  = (const float*)d_in[2];
    const float* p2  = (const float*)d_in[3];
    const float* p3  = (const float*)d_in[4];
    const float* p4  = (const float*)d_in[5];
    float* out = (float*)d_out;

    char* ws = (char*)d_ws;
    float* scores    = (float*)(ws + 0);          // 5000 floats
    int*   rank      = (int*)(ws + 20000);        // 5000 ints
    int*   topk_idx  = (int*)(ws + 40000);        // 1000 ints
    int*   slot_det  = (int*)(ws + 44000);        // 1000 ints
    int*   slot_lvl  = (int*)(ws + 48000);        // 1000 ints
    int*   counter   = (int*)(ws + 52000);        // 1 int
    int*   worklist  = (int*)(ws + 52096);        // up to 196000 ints

    zero_kernel<<<6125, 256, 0, stream>>>(out);
    scores_kernel<<<(NDET + 255) / 256, 256, 0, stream>>>(det, scores, rank, counter);
    dim3 rg((NDET + ICHUNK - 1) / ICHUNK, NDET / JCHUNK);
    rank_kernel<<<rg, ICHUNK, 0, stream>>>(scores, rank);
    scatter_kernel<<<(NDET + 255) / 256, 256, 0, stream>>>(rank, topk_idx);
    order_kernel<<<1, 1024, 0, stream>>>(det, topk_idx, slot_det, slot_lvl);
    worklist_kernel<<<(NPAIR + 255) / 256, 256, 0, stream>>>(det, slot_det, slot_lvl,
                                                             counter, worklist);
    gather_kernel<<<GBLOCKS, 256, 0, stream>>>(det, p0, p1, p2, p3, p4,
                                               slot_det, slot_lvl, counter, worklist, out);
}

// Round 5
// 290.506 us; speedup vs baseline: 1.1114x; 1.1114x over previous
//
#include <hip/hip_runtime.h>

#define NDET 5000
#define NCLS 80
#define DSTR 84      // 4 box coords + 80 class scores
#define TOPK 1000
#define CROP 14
#define NPIX (CROP * CROP)   // 196
#define C    256

#define JCHUNK 250
#define ICHUNK 256

typedef float v4f __attribute__((ext_vector_type(4)));

// ---------------- Phase 1a: scores + zero the rank array --------------------
__global__ void scores_kernel(const float* __restrict__ det, float* __restrict__ scores,
                              int* __restrict__ rank) {
    int i = blockIdx.x * blockDim.x + threadIdx.x;
    if (i >= NDET) return;
    const float* row = det + i * DSTR + 4;
    float m = row[0];
    #pragma unroll
    for (int c = 1; c < NCLS; ++c) m = fmaxf(m, row[c]);
    scores[i] = m;
    rank[i] = 0;
}

// ---------------- Phase 1b: distributed rank counting -----------------------
// rank(i) = #{j : s_j > s_i} + #{j < i : s_j == s_i}   (jax.lax.top_k order)
// 400 blocks; atomics land on 5000 distinct addresses (20 hits each) — no
// single-address hot spot (unlike the R4 worklist counter).
__global__ __launch_bounds__(ICHUNK) void rank_kernel(const float* __restrict__ scores,
                                                      int* __restrict__ rank) {
    __shared__ float s[JCHUNK];
    int jbase = blockIdx.y * JCHUNK;
    for (int t = threadIdx.x; t < JCHUNK; t += blockDim.x) s[t] = scores[jbase + t];
    __syncthreads();
    int i = blockIdx.x * ICHUNK + threadIdx.x;
    if (i >= NDET) return;
    float my = scores[i];
    int r = 0;
    #pragma unroll 5
    for (int t = 0; t < JCHUNK; ++t) {
        float v = s[t];
        int j = jbase + t;
        r += (v > my) | ((v == my) & (j < i));
    }
    atomicAdd(&rank[i], r);
}

// ---------------- Phase 1c: scatter (fused) + levels + stable counting sort -
// Scatter rank->topk_idx in LDS, then packed-key prefix scan for the stable
// level sort. key(r) = 1 << 12*L (5 levels, counts < 4096).
__global__ __launch_bounds__(1024) void order_kernel(const float* __restrict__ det,
                                                     const int* __restrict__ rank,
                                                     int* __restrict__ slot_det,
                                                     int* __restrict__ slot_level) {
    __shared__ int topk_idx_s[TOPK];
    __shared__ unsigned long long wave_tot[16];
    int r = threadIdx.x;
    for (int i = r; i < NDET; i += 1024) {
        int rk = rank[i];
        if (rk < TOPK) topk_idx_s[rk] = i;
    }
    __syncthreads();

    int di = 0, L = 0;
    unsigned long long key = 0;
    if (r < TOPK) {
        di = topk_idx_s[r];
        const float* b = det + di * DSTR;
        float w = b[2] - b[0];
        float h = b[3] - b[1];
        float sz = sqrtf(w * h);
        float lf = floorf(1.0f + log2f(sz / 224.0f + 1e-7f));
        lf = fminf(fmaxf(lf, 0.0f), 4.0f);
        L = (int)lf;
        key = 1ULL << (12 * L);
    }
    unsigned long long incl = key;
    #pragma unroll
    for (int d = 1; d < 64; d <<= 1) {
        unsigned long long up = __shfl_up(incl, d, 64);
        if ((r & 63) >= d) incl += up;
    }
    int wave = r >> 6;
    if ((r & 63) == 63) wave_tot[wave] = incl;
    __syncthreads();
    unsigned long long waveoff = 0, total = 0;
    for (int w = 0; w < 16; ++w) {
        unsigned long long t = wave_tot[w];
        if (w < wave) waveoff += t;
        total += t;
    }
    if (r < TOPK) {
        unsigned long long excl = waveoff + incl - key;
        int base = 0;
        for (int l = 0; l < L; ++l) base += (int)((total >> (12 * l)) & 0xFFF);
        int within = (int)((excl >> (12 * L)) & 0xFFF);
        int pos = base + within;
        slot_det[pos] = di;
        slot_level[pos] = L;
    }
}

// ---------------- Phase 2: crop_and_resize main kernel ----------------------
// 13 blocks per box, 4 waves/block, 4 consecutive pixels per wave (4 stores
// in flight). Box/level loads are block-uniform -> scalar loads. All control
// flow is wave-uniform (64 lanes share one pixel). Lane = 4 channels (v4f),
// 1 KB per store instruction.
__global__ __launch_bounds__(256) void crop_kernel(
    const float* __restrict__ det,
    const float* __restrict__ p0, const float* __restrict__ p1,
    const float* __restrict__ p2, const float* __restrict__ p3,
    const float* __restrict__ p4,
    const int* __restrict__ slot_det, const int* __restrict__ slot_level,
    float* __restrict__ out)
{
    int wave = threadIdx.x >> 6;
    int lane = threadIdx.x & 63;
    int slot = blockIdx.x / 13;
    int sub  = blockIdx.x % 13;
    int pbase = sub * 16 + wave * 4;      // first of 4 consecutive pixels

    int di = slot_det[slot];
    int L  = slot_level[slot];

    const float* feat; int H;
    switch (L) {
        case 0:  feat = p0; H = 256; break;
        case 1:  feat = p1; H = 128; break;
        case 2:  feat = p2; H = 64;  break;
        case 3:  feat = p3; H = 32;  break;
        default: feat = p4; H = 16;  break;
    }
    float hf = (float)(H - 1);

    const float* b = det + di * DSTR;
    float x1n = b[0] / hf, y1n = b[1] / hf;
    float x2n = b[2] / hf, y2n = b[3] / hf;   // W == H per level
    float* outbase = out + (size_t)slot * NPIX * C;

    #pragma unroll
    for (int j = 0; j < 4; ++j) {
        int p = pbase + j;
        if (p >= NPIX) break;
        int py = p / CROP;
        int px = p - py * CROP;
        float ty = (float)py / 13.0f;
        float tx = (float)px / 13.0f;
        float ys = (y1n + (y2n - y1n) * ty) * hf;
        float xs = (x1n + (x2n - x1n) * tx) * hf;

        v4f* outp = (v4f*)(outbase + (size_t)p * C) + lane;

        bool valid = (ys >= 0.0f) & (ys <= hf) & (xs >= 0.0f) & (xs <= hf);
        if (!valid) {
            v4f z = {0.0f, 0.0f, 0.0f, 0.0f};
            *outp = z;
            continue;
        }

        float y0f = floorf(ys), x0f = floorf(xs);
        float ly = ys - y0f,    lx = xs - x0f;
        int y0i = (int)fminf(fmaxf(y0f,        0.0f), hf);
        int y1i = (int)fminf(fmaxf(y0f + 1.0f, 0.0f), hf);
        int x0i = (int)fminf(fmaxf(x0f,        0.0f), hf);
        int x1i = (int)fminf(fmaxf(x0f + 1.0f, 0.0f), hf);

        v4f f00 = ((const v4f*)(feat + (size_t)(y0i * H + x0i) * C))[lane];
        v4f f01 = ((const v4f*)(feat + (size_t)(y0i * H + x1i) * C))[lane];
        v4f f10 = ((const v4f*)(feat + (size_t)(y1i * H + x0i) * C))[lane];
        v4f f11 = ((const v4f*)(feat + (size_t)(y1i * H + x1i) * C))[lane];

        v4f top = f00 + (f01 - f00) * lx;
        v4f bot = f10 + (f11 - f10) * lx;
        v4f o   = top + (bot - top) * ly;
        *outp = o;
    }
}

extern "C" void kernel_launch(void* const* d_in, const int* in_sizes, int n_in,
                              void* d_out, int out_size, void* d_ws, size_t ws_size,
                              hipStream_t stream) {
    const float* det = (const float*)d_in[0];
    const float* p0  = (const float*)d_in[1];
    const float* p1  = (const float*)d_in[2];
    const float* p2  = (const float*)d_in[3];
    const float* p3  = (const float*)d_in[4];
    const float* p4  = (const float*)d_in[5];
    float* out = (float*)d_out;

    char* ws = (char*)d_ws;
    float* scores    = (float*)(ws + 0);          // 5000 floats
    int*   rank      = (int*)(ws + 20000);        // 5000 ints
    int*   slot_det  = (int*)(ws + 40000);        // 1000 ints
    int*   slot_lvl  = (int*)(ws + 44000);        // 1000 ints

    scores_kernel<<<(NDET + 255) / 256, 256, 0, stream>>>(det, scores, rank);
    dim3 rg((NDET + ICHUNK - 1) / ICHUNK, NDET / JCHUNK);
    rank_kernel<<<rg, ICHUNK, 0, stream>>>(scores, rank);
    order_kernel<<<1, 1024, 0, stream>>>(det, rank, slot_det, slot_lvl);
    crop_kernel<<<TOPK * 13, 256, 0, stream>>>(det, p0, p1, p2, p3, p4,
                                               slot_det, slot_lvl, out);
}

// Round 6
// 281.585 us; speedup vs baseline: 1.1466x; 1.0317x over previous
//
#include <hip/hip_runtime.h>

#define NDET 5000
#define NCLS 80
#define DSTR 84      // 4 box coords + 80 class scores
#define TOPK 1000
#define CROP 14
#define NPIX (CROP * CROP)   // 196
#define C    256

#define JCHUNK 250
#define ICHUNK 256

typedef float v4f __attribute__((ext_vector_type(4)));

// ---------------- Phase 1a: scores (vectorized) + level per detection -------
__global__ void scores_kernel(const float* __restrict__ det, float* __restrict__ scores,
                              int* __restrict__ rank, int* __restrict__ lvl_all) {
    int i = blockIdx.x * blockDim.x + threadIdx.x;
    if (i >= NDET) return;
    const float* row = det + i * DSTR;
    // class scores at row+4: 80 floats, 16B-aligned (336*i + 16)
    const v4f* cls = (const v4f*)(row + 4);
    v4f m4 = cls[0];
    #pragma unroll
    for (int c = 1; c < NCLS / 4; ++c) {
        v4f v = cls[c];
        m4.x = fmaxf(m4.x, v.x); m4.y = fmaxf(m4.y, v.y);
        m4.z = fmaxf(m4.z, v.z); m4.w = fmaxf(m4.w, v.w);
    }
    scores[i] = fmaxf(fmaxf(m4.x, m4.y), fmaxf(m4.z, m4.w));
    rank[i] = 0;
    // level = clip(floor(1 + log2(sqrt(w*h)/224 + 1e-7)), 0, 4)
    float w = row[2] - row[0];
    float h = row[3] - row[1];
    float sz = sqrtf(w * h);
    float lf = floorf(1.0f + log2f(sz / 224.0f + 1e-7f));
    lf = fminf(fmaxf(lf, 0.0f), 4.0f);
    lvl_all[i] = (int)lf;
}

// ---------------- Phase 1b: distributed rank counting -----------------------
// rank(i) = #{j : s_j > s_i} + #{j < i : s_j == s_i}   (jax.lax.top_k order)
__global__ __launch_bounds__(ICHUNK) void rank_kernel(const float* __restrict__ scores,
                                                      int* __restrict__ rank) {
    __shared__ float s[JCHUNK];
    int jbase = blockIdx.y * JCHUNK;
    for (int t = threadIdx.x; t < JCHUNK; t += blockDim.x) s[t] = scores[jbase + t];
    __syncthreads();
    int i = blockIdx.x * ICHUNK + threadIdx.x;
    if (i >= NDET) return;
    float my = scores[i];
    int r = 0;
    #pragma unroll 5
    for (int t = 0; t < JCHUNK; ++t) {
        float v = s[t];
        int j = jbase + t;
        r += (v > my) | ((v == my) & (j < i));
    }
    atomicAdd(&rank[i], r);
}

// ---------------- Phase 1c: scatter + stable level sort + per-slot params ---
// Scatter rank->topk_idx in LDS; packed-key prefix scan (5 levels, counts
// < 4096) for the stable sort; then precompute everything crop needs per
// slot: {x1n, y1n, x2n-x1n, y2n-y1n} with the SAME float ops as reference.
__global__ __launch_bounds__(1024) void order_kernel(const float* __restrict__ det,
                                                     const int* __restrict__ rank,
                                                     const int* __restrict__ lvl_all,
                                                     v4f* __restrict__ slot_params,
                                                     int* __restrict__ slot_level) {
    __shared__ int topk_idx_s[TOPK];
    __shared__ unsigned long long wave_tot[16];
    int r = threadIdx.x;
    for (int i = r; i < NDET; i += 1024) {
        int rk = rank[i];
        if (rk < TOPK) topk_idx_s[rk] = i;
    }
    __syncthreads();

    int di = 0, L = 0;
    unsigned long long key = 0;
    if (r < TOPK) {
        di = topk_idx_s[r];
        L = lvl_all[di];
        key = 1ULL << (12 * L);
    }
    unsigned long long incl = key;
    #pragma unroll
    for (int d = 1; d < 64; d <<= 1) {
        unsigned long long up = __shfl_up(incl, d, 64);
        if ((r & 63) >= d) incl += up;
    }
    int wave = r >> 6;
    if ((r & 63) == 63) wave_tot[wave] = incl;
    __syncthreads();
    unsigned long long waveoff = 0, total = 0;
    for (int w = 0; w < 16; ++w) {
        unsigned long long t = wave_tot[w];
        if (w < wave) waveoff += t;
        total += t;
    }
    if (r < TOPK) {
        unsigned long long excl = waveoff + incl - key;
        int base = 0;
        for (int l = 0; l < L; ++l) base += (int)((total >> (12 * l)) & 0xFFF);
        int within = (int)((excl >> (12 * L)) & 0xFFF);
        int pos = base + within;
        int H = 256 >> L;
        float hf = (float)(H - 1);
        const float* b = det + di * DSTR;
        float x1n = b[0] / hf, y1n = b[1] / hf;
        float x2n = b[2] / hf, y2n = b[3] / hf;   // W == H per level
        v4f prm = {x1n, y1n, x2n - x1n, y2n - y1n};
        slot_params[pos] = prm;
        slot_level[pos] = L;
    }
}

// ---------------- Phase 2: crop_and_resize main kernel ----------------------
// Best-measured structure (R2): 49 blocks/box, 1 wave = 1 pixel, lane = 4
// contiguous channels (16B store). Per-wave preamble is now just one scalar
// 16B param load + 4B level load (no divisions, no det access).
__global__ __launch_bounds__(256) void crop_kernel(
    const float* __restrict__ p0, const float* __restrict__ p1,
    const float* __restrict__ p2, const float* __restrict__ p3,
    const float* __restrict__ p4,
    const v4f* __restrict__ slot_params, const int* __restrict__ slot_level,
    float* __restrict__ out)
{
    int wave = threadIdx.x >> 6;
    int lane = threadIdx.x & 63;
    int slot = blockIdx.x / 49;
    int p    = (blockIdx.x % 49) * 4 + wave;   // pixel index 0..195
    int py = p / CROP, px = p - py * CROP;

    int L = slot_level[slot];
    const float* feat;
    switch (L) {
        case 0:  feat = p0; break;
        case 1:  feat = p1; break;
        case 2:  feat = p2; break;
        case 3:  feat = p3; break;
        default: feat = p4; break;
    }
    int H = 256 >> L;
    float hf = (float)(H - 1);

    v4f prm = slot_params[slot];
    float ty = (float)py / 13.0f;
    float tx = (float)px / 13.0f;
    float ys = (prm.y + prm.w * ty) * hf;
    float xs = (prm.x + prm.z * tx) * hf;

    v4f* outp = (v4f*)(out + (size_t)(slot * NPIX + p) * C) + lane;

    bool valid = (ys >= 0.0f) & (ys <= hf) & (xs >= 0.0f) & (xs <= hf);
    if (!valid) {
        v4f z = {0.0f, 0.0f, 0.0f, 0.0f};
        *outp = z;
        return;
    }

    float y0f = floorf(ys), x0f = floorf(xs);
    float ly = ys - y0f,    lx = xs - x0f;
    int y0i = (int)fminf(fmaxf(y0f,        0.0f), hf);
    int y1i = (int)fminf(fmaxf(y0f + 1.0f, 0.0f), hf);
    int x0i = (int)fminf(fmaxf(x0f,        0.0f), hf);
    int x1i = (int)fminf(fmaxf(x0f + 1.0f, 0.0f), hf);

    v4f f00 = ((const v4f*)(feat + (size_t)(y0i * H + x0i) * C))[lane];
    v4f f01 = ((const v4f*)(feat + (size_t)(y0i * H + x1i) * C))[lane];
    v4f f10 = ((const v4f*)(feat + (size_t)(y1i * H + x0i) * C))[lane];
    v4f f11 = ((const v4f*)(feat + (size_t)(y1i * H + x1i) * C))[lane];

    v4f top = f00 + (f01 - f00) * lx;
    v4f bot = f10 + (f11 - f10) * lx;
    v4f o   = top + (bot - top) * ly;
    *outp = o;
}

extern "C" void kernel_launch(void* const* d_in, const int* in_sizes, int n_in,
                              void* d_out, int out_size, void* d_ws, size_t ws_size,
                              hipStream_t stream) {
    const float* det = (const float*)d_in[0];
    const float* p0  = (const float*)d_in[1];
    const float* p1  = (const float*)d_in[2];
    const float* p2  = (const float*)d_in[3];
    const float* p3  = (const float*)d_in[4];
    const float* p4  = (const float*)d_in[5];
    float* out = (float*)d_out;

    char* ws = (char*)d_ws;
    float* scores      = (float*)(ws + 0);        // 5000 floats
    int*   rank        = (int*)(ws + 20000);      // 5000 ints
    int*   lvl_all     = (int*)(ws + 40000);      // 5000 ints
    v4f*   slot_params = (v4f*)(ws + 60000);      // 1000 float4 (16B-aligned)
    int*   slot_lvl    = (int*)(ws + 76000);      // 1000 ints

    scores_kernel<<<(NDET + 255) / 256, 256, 0, stream>>>(det, scores, rank, lvl_all);
    dim3 rg((NDET + ICHUNK - 1) / ICHUNK, NDET / JCHUNK);
    rank_kernel<<<rg, ICHUNK, 0, stream>>>(scores, rank);
    order_kernel<<<1, 1024, 0, stream>>>(det, rank, lvl_all, slot_params, slot_lvl);
    crop_kernel<<<TOPK * 49, 256, 0, stream>>>(p0, p1, p2, p3, p4,
                                               slot_params, slot_lvl, out);
}